// Round 2
// baseline (516.414 us; speedup 1.0000x reference)
//
#include <hip/hip_runtime.h>
#include <hip/hip_bf16.h>
#include <math.h>

typedef __bf16 bf16;
typedef __bf16 bf16x8 __attribute__((ext_vector_type(8)));
typedef __bf16 bf16x4 __attribute__((ext_vector_type(4)));
typedef float f32x4 __attribute__((ext_vector_type(4)));

static constexpr int B_ = 4, T_ = 2048, C_ = 1024, H_ = 16, D_ = 64;
static constexpr int M_ = B_ * T_;   // 8192 rows
static constexpr int NQKV = 3 * C_;  // 3072
static constexpr int K_ = C_;        // 1024 (GEMM reduction dim)

__device__ __forceinline__ bf16 to_bf16(float f) { return (bf16)f; }

// ---------------- fp32 -> bf16 elementwise convert (x) ----------------
__global__ void cvt_x_kernel(const float* __restrict__ in, bf16* __restrict__ out) {
  int i = (blockIdx.x * blockDim.x + threadIdx.x) * 4;
  float4 v = *reinterpret_cast<const float4*>(in + i);
  bf16x4 o;
  o[0] = to_bf16(v.x); o[1] = to_bf16(v.y); o[2] = to_bf16(v.z); o[3] = to_bf16(v.w);
  *reinterpret_cast<bf16x4*>(out + i) = o;
}

// ------------- fp32 [ROWS][COLS] -> bf16 [COLS][ROWS] transpose -------------
__global__ void transpose_cvt_kernel(const float* __restrict__ in, bf16* __restrict__ out,
                                     int ROWS, int COLS) {
  __shared__ float tile[32][33];
  int c0 = blockIdx.x * 32, r0 = blockIdx.y * 32;
  int tx = threadIdx.x, ty = threadIdx.y;  // 32 x 8
#pragma unroll
  for (int i = 0; i < 32; i += 8)
    tile[ty + i][tx] = in[(size_t)(r0 + ty + i) * COLS + c0 + tx];
  __syncthreads();
#pragma unroll
  for (int i = 0; i < 32; i += 8)
    out[(size_t)(c0 + ty + i) * ROWS + r0 + tx] = to_bf16(tile[tx][ty + i]);
}

// ---------------- bf16 MFMA GEMM, 128x128 tile, BK=32 ----------------
// A: [M][K] row-major bf16.  Bt: [N][K] row-major bf16 (i.e. B transposed).
// QKV=true : N=3072, epilogue adds bias and scatters q (scaled), k -> [B,H,T,D],
//            v -> [B,H,D,T] (transposed), all bf16.
// QKV=false: N=1024, epilogue adds bias, writes fp32 C [M][1024].
template <bool QKV>
__global__ __launch_bounds__(256) void gemm_kernel(
    const bf16* __restrict__ A, const bf16* __restrict__ Bt,
    const float* __restrict__ bias,
    bf16* __restrict__ qo, bf16* __restrict__ ko, bf16* __restrict__ vo,
    float* __restrict__ co) {
  __shared__ bf16 As[128][40];  // +8 bf16 pad: row stride 80B -> 2-way banks (free)
  __shared__ bf16 Bs[128][40];
  const int bm = blockIdx.x, bn = blockIdx.y;
  const int tid = threadIdx.x;
  const int lane = tid & 63, wave = tid >> 6;
  const int wm = wave >> 1, wn = wave & 1;  // 2x2 waves, 64x64 each
  const int l15 = lane & 15, lg = lane >> 4;
  const int kslot = lg * 8;
  const int srow = tid >> 2, schunk = (tid & 3) * 8;

  f32x4 acc[4][4] = {};

  const bf16* aptr = A + (size_t)(bm * 128 + srow) * K_ + schunk;
  const bf16* bptr = Bt + (size_t)(bn * 128 + srow) * K_ + schunk;

  for (int k0 = 0; k0 < K_; k0 += 32) {
    *reinterpret_cast<bf16x8*>(&As[srow][schunk]) =
        *reinterpret_cast<const bf16x8*>(aptr + k0);
    *reinterpret_cast<bf16x8*>(&As[srow + 64][schunk]) =
        *reinterpret_cast<const bf16x8*>(aptr + (size_t)64 * K_ + k0);
    *reinterpret_cast<bf16x8*>(&Bs[srow][schunk]) =
        *reinterpret_cast<const bf16x8*>(bptr + k0);
    *reinterpret_cast<bf16x8*>(&Bs[srow + 64][schunk]) =
        *reinterpret_cast<const bf16x8*>(bptr + (size_t)64 * K_ + k0);
    __syncthreads();
    bf16x8 af[4], bfr[4];
#pragma unroll
    for (int m = 0; m < 4; ++m)
      af[m] = *reinterpret_cast<const bf16x8*>(&As[wm * 64 + m * 16 + l15][kslot]);
#pragma unroll
    for (int n = 0; n < 4; ++n)
      bfr[n] = *reinterpret_cast<const bf16x8*>(&Bs[wn * 64 + n * 16 + l15][kslot]);
#pragma unroll
    for (int m = 0; m < 4; ++m)
#pragma unroll
      for (int n = 0; n < 4; ++n)
        acc[m][n] = __builtin_amdgcn_mfma_f32_16x16x32_bf16(af[m], bfr[n], acc[m][n], 0, 0, 0);
    __syncthreads();
  }

  const int colbase = bn * 128 + wn * 64;
  const int rowbase = bm * 128 + wm * 64;
  if (QKV) {
    const int sec = (bn * 128) >> 10;  // 0=q 1=k 2=v (block-uniform: 128 | 1024)
#pragma unroll
    for (int n = 0; n < 4; ++n) {
      const int col = colbase + n * 16 + l15;
      const float bv = bias[col];
      const int cc = col & 1023;
      const int h = cc >> 6, d = cc & 63;
#pragma unroll
      for (int m = 0; m < 4; ++m) {
#pragma unroll
        for (int r = 0; r < 4; ++r) {
          const int row = rowbase + m * 16 + lg * 4 + r;
          const int b = row >> 11, t = row & 2047;
          const float v = acc[m][n][r] + bv;
          if (sec == 0)
            qo[((size_t)(b * 16 + h) * 2048 + t) * 64 + d] = to_bf16(v * 0.125f);
          else if (sec == 1)
            ko[((size_t)(b * 16 + h) * 2048 + t) * 64 + d] = to_bf16(v);
          else
            vo[((size_t)(b * 16 + h) * 64 + d) * 2048 + t] = to_bf16(v);
        }
      }
    }
  } else {
#pragma unroll
    for (int n = 0; n < 4; ++n) {
      const int col = colbase + n * 16 + l15;
      const float bv = bias[col];
#pragma unroll
      for (int m = 0; m < 4; ++m) {
#pragma unroll
        for (int r = 0; r < 4; ++r) {
          const int row = rowbase + m * 16 + lg * 4 + r;
          co[(size_t)row * 1024 + col] = acc[m][n][r] + bv;
        }
      }
    }
  }
}

// ---------------- causal flash attention ----------------
// q,k: [B,H,T,D] bf16 (q pre-scaled by 1/8). vT: [B,H,D,T] bf16.
// o: [B,T,C] bf16. Block = 128 q-rows of one (b,h); 4 waves x 32 rows.
__global__ __launch_bounds__(256) void attn_kernel(
    const bf16* __restrict__ q, const bf16* __restrict__ k,
    const bf16* __restrict__ vT, bf16* __restrict__ o) {
  __shared__ bf16 Pl[4][32][72];  // per-wave P buffer; 144B pitch = 16B-aligned, 2-way banks
  const int blk = blockIdx.x;
  const int bh = blk >> 4;   // 0..63
  const int qt = blk & 15;   // 16 q-tiles of 128
  const int qb = qt * 128;
  const int tid = threadIdx.x, lane = tid & 63, w = tid >> 6;
  const int l15 = lane & 15, lg = lane >> 4, kslot = lg * 8;
  const bf16* qp = q + (size_t)bh * T_ * D_;
  const bf16* kp = k + (size_t)bh * T_ * D_;
  const bf16* vp = vT + (size_t)bh * D_ * T_;
  const int qrow0 = qb + w * 32;

  // Q fragments held in registers for the whole kernel
  bf16x8 qf[2][2];
#pragma unroll
  for (int m = 0; m < 2; ++m)
#pragma unroll
    for (int kf = 0; kf < 2; ++kf)
      qf[m][kf] = *reinterpret_cast<const bf16x8*>(
          &qp[(size_t)(qrow0 + m * 16 + l15) * D_ + kf * 32 + kslot]);

  f32x4 of[2][4] = {};
  float mrun[2][4], lrun[2][4];
#pragma unroll
  for (int m = 0; m < 2; ++m)
#pragma unroll
    for (int r = 0; r < 4; ++r) { mrun[m][r] = -INFINITY; lrun[m][r] = 0.f; }

  for (int tb = 0; tb <= qrow0 + 31; tb += 64) {  // per-wave trip count (no block sync inside)
    f32x4 sf[2][4] = {};
#pragma unroll
    for (int nf = 0; nf < 4; ++nf) {
#pragma unroll
      for (int kf = 0; kf < 2; ++kf) {
        bf16x8 kb = *reinterpret_cast<const bf16x8*>(
            &kp[(size_t)(tb + nf * 16 + l15) * D_ + kf * 32 + kslot]);
#pragma unroll
        for (int m = 0; m < 2; ++m)
          sf[m][nf] = __builtin_amdgcn_mfma_f32_16x16x32_bf16(qf[m][kf], kb, sf[m][nf], 0, 0, 0);
      }
    }
    const bool need_mask = (tb + 63) > qrow0;
#pragma unroll
    for (int m = 0; m < 2; ++m) {
#pragma unroll
      for (int r = 0; r < 4; ++r) {
        const int row = qrow0 + m * 16 + lg * 4 + r;
        if (need_mask) {
#pragma unroll
          for (int nf = 0; nf < 4; ++nf)
            if (tb + nf * 16 + l15 > row) sf[m][nf][r] = -1e30f;
        }
        float mx = fmaxf(fmaxf(sf[m][0][r], sf[m][1][r]), fmaxf(sf[m][2][r], sf[m][3][r]));
        mx = fmaxf(mx, __shfl_xor(mx, 1));
        mx = fmaxf(mx, __shfl_xor(mx, 2));
        mx = fmaxf(mx, __shfl_xor(mx, 4));
        mx = fmaxf(mx, __shfl_xor(mx, 8));
        const float mnew = fmaxf(mrun[m][r], mx);
        const float corr = __expf(mrun[m][r] - mnew);
        float rs = 0.f;
#pragma unroll
        for (int nf = 0; nf < 4; ++nf) {
          const float p = __expf(sf[m][nf][r] - mnew);
          sf[m][nf][r] = p;
          rs += p;
        }
        rs += __shfl_xor(rs, 1);
        rs += __shfl_xor(rs, 2);
        rs += __shfl_xor(rs, 4);
        rs += __shfl_xor(rs, 8);
        lrun[m][r] = lrun[m][r] * corr + rs;
        mrun[m][r] = mnew;
#pragma unroll
        for (int nd = 0; nd < 4; ++nd) of[m][nd][r] *= corr;
      }
    }
    // P: C-layout -> LDS -> A-layout
#pragma unroll
    for (int m = 0; m < 2; ++m)
#pragma unroll
      for (int nf = 0; nf < 4; ++nf)
#pragma unroll
        for (int r = 0; r < 4; ++r)
          Pl[w][m * 16 + lg * 4 + r][nf * 16 + l15] = to_bf16(sf[m][nf][r]);
    asm volatile("s_waitcnt lgkmcnt(0)" ::: "memory");
    bf16x8 pa[2][2];
#pragma unroll
    for (int m = 0; m < 2; ++m)
#pragma unroll
      for (int kf = 0; kf < 2; ++kf)
        pa[m][kf] = *reinterpret_cast<const bf16x8*>(&Pl[w][m * 16 + l15][kf * 32 + kslot]);
#pragma unroll
    for (int nd = 0; nd < 4; ++nd) {
#pragma unroll
      for (int kf = 0; kf < 2; ++kf) {
        bf16x8 vb = *reinterpret_cast<const bf16x8*>(
            &vp[(size_t)(nd * 16 + l15) * T_ + tb + kf * 32 + kslot]);
#pragma unroll
        for (int m = 0; m < 2; ++m)
          of[m][nd] = __builtin_amdgcn_mfma_f32_16x16x32_bf16(pa[m][kf], vb, of[m][nd], 0, 0, 0);
      }
    }
  }

  const int b = bh >> 4, h = bh & 15;
  bf16* op = o + (size_t)b * T_ * C_ + h * 64;
#pragma unroll
  for (int m = 0; m < 2; ++m) {
#pragma unroll
    for (int r = 0; r < 4; ++r) {
      const int row = qrow0 + m * 16 + lg * 4 + r;
      const float inv = 1.f / lrun[m][r];
#pragma unroll
      for (int nd = 0; nd < 4; ++nd)
        op[(size_t)row * C_ + nd * 16 + l15] = to_bf16(of[m][nd][r] * inv);
    }
  }
}

extern "C" void kernel_launch(void* const* d_in, const int* in_sizes, int n_in,
                              void* d_out, int out_size, void* d_ws, size_t ws_size,
                              hipStream_t stream) {
  const float* x      = (const float*)d_in[0];
  const float* w_attn = (const float*)d_in[1];
  const float* b_attn = (const float*)d_in[2];
  const float* w_proj = (const float*)d_in[3];
  const float* b_proj = (const float*)d_in[4];
  float* out = (float*)d_out;

  char* ws = (char*)d_ws;
  size_t off = 0;
  bf16* xb  = (bf16*)(ws + off); off += (size_t)M_ * K_ * 2;      // 16 MiB (reused as attn_out)
  bf16* wta = (bf16*)(ws + off); off += (size_t)NQKV * K_ * 2;    // 6 MiB  [3072][1024]
  bf16* wtp = (bf16*)(ws + off); off += (size_t)C_ * K_ * 2;      // 2 MiB  [1024][1024]
  bf16* qb  = (bf16*)(ws + off); off += (size_t)M_ * C_ * 2;      // 16 MiB [B,H,T,D]
  bf16* kb  = (bf16*)(ws + off); off += (size_t)M_ * C_ * 2;      // 16 MiB [B,H,T,D]
  bf16* vtb = (bf16*)(ws + off); off += (size_t)M_ * C_ * 2;      // 16 MiB [B,H,D,T]
  bf16* attn_out = xb;  // x no longer needed once QKV GEMM is done

  // 1. convert x
  cvt_x_kernel<<<(M_ * K_) / (4 * 256), 256, 0, stream>>>(x, xb);
  // 2. transpose+convert weights
  transpose_cvt_kernel<<<dim3(NQKV / 32, K_ / 32), dim3(32, 8), 0, stream>>>(w_attn, wta, K_, NQKV);
  transpose_cvt_kernel<<<dim3(C_ / 32, K_ / 32), dim3(32, 8), 0, stream>>>(w_proj, wtp, K_, C_);
  // 3. QKV GEMM (fused bias + q-scale + layout scatter)
  gemm_kernel<true><<<dim3(M_ / 128, NQKV / 128), 256, 0, stream>>>(
      xb, wta, b_attn, qb, kb, vtb, nullptr);
  // 4. causal flash attention
  attn_kernel<<<64 * (T_ / 128), 256, 0, stream>>>(qb, kb, vtb, attn_out);
  // 5. output projection (bias, fp32 out)
  gemm_kernel<false><<<dim3(M_ / 128, C_ / 128), 256, 0, stream>>>(
      attn_out, wtp, b_proj, nullptr, nullptr, nullptr, out);
}

// Round 9
// 323.788 us; speedup vs baseline: 1.5949x; 1.5949x over previous
//
#include <hip/hip_runtime.h>
#include <hip/hip_bf16.h>
#include <math.h>

typedef __bf16 bf16;
typedef __bf16 bf16x8 __attribute__((ext_vector_type(8)));
typedef __bf16 bf16x4 __attribute__((ext_vector_type(4)));
typedef __bf16 bf16x2 __attribute__((ext_vector_type(2)));
typedef float f32x4 __attribute__((ext_vector_type(4)));
typedef float f32x16 __attribute__((ext_vector_type(16)));
typedef int int4v __attribute__((ext_vector_type(4)));

static constexpr int B_ = 4, T_ = 2048, C_ = 1024, H_ = 16, D_ = 64;
static constexpr int M_ = B_ * T_;   // 8192 rows
static constexpr int NQKV = 3 * C_;  // 3072
static constexpr int K_ = C_;        // 1024 (GEMM reduction dim)

__device__ __forceinline__ bf16 to_bf16(float f) { return (bf16)f; }

// ---------------- fp32 -> bf16 elementwise convert (x) ----------------
__global__ void cvt_x_kernel(const float* __restrict__ in, bf16* __restrict__ out) {
  int i = (blockIdx.x * blockDim.x + threadIdx.x) * 4;
  float4 v = *reinterpret_cast<const float4*>(in + i);
  bf16x4 o;
  o[0] = to_bf16(v.x); o[1] = to_bf16(v.y); o[2] = to_bf16(v.z); o[3] = to_bf16(v.w);
  *reinterpret_cast<bf16x4*>(out + i) = o;
}

// ------------- fp32 [ROWS][COLS] -> bf16 [COLS][ROWS] transpose -------------
__global__ void transpose_cvt_kernel(const float* __restrict__ in, bf16* __restrict__ out,
                                     int ROWS, int COLS) {
  __shared__ float tile[32][33];
  int c0 = blockIdx.x * 32, r0 = blockIdx.y * 32;
  int tx = threadIdx.x, ty = threadIdx.y;  // 32 x 8
#pragma unroll
  for (int i = 0; i < 32; i += 8)
    tile[ty + i][tx] = in[(size_t)(r0 + ty + i) * COLS + c0 + tx];
  __syncthreads();
#pragma unroll
  for (int i = 0; i < 32; i += 8)
    out[(size_t)(c0 + ty + i) * ROWS + r0 + tx] = to_bf16(tile[tx][ty + i]);
}

// ---------------- bf16 MFMA GEMM, 128x128 tile, BK=32 ----------------
template <bool QKV>
__global__ __launch_bounds__(256) void gemm_kernel(
    const bf16* __restrict__ A, const bf16* __restrict__ Bt,
    const float* __restrict__ bias,
    bf16* __restrict__ qo, bf16* __restrict__ ko, bf16* __restrict__ vo,
    float* __restrict__ co) {
  __shared__ bf16 As[128][40];  // +8 bf16 pad: row stride 80B -> 2-way banks (free)
  __shared__ bf16 Bs[128][40];
  const int bm = blockIdx.x, bn = blockIdx.y;
  const int tid = threadIdx.x;
  const int lane = tid & 63, wave = tid >> 6;
  const int wm = wave >> 1, wn = wave & 1;  // 2x2 waves, 64x64 each
  const int l15 = lane & 15, lg = lane >> 4;
  const int kslot = lg * 8;
  const int srow = tid >> 2, schunk = (tid & 3) * 8;

  f32x4 acc[4][4] = {};

  const bf16* aptr = A + (size_t)(bm * 128 + srow) * K_ + schunk;
  const bf16* bptr = Bt + (size_t)(bn * 128 + srow) * K_ + schunk;

  for (int k0 = 0; k0 < K_; k0 += 32) {
    *reinterpret_cast<bf16x8*>(&As[srow][schunk]) =
        *reinterpret_cast<const bf16x8*>(aptr + k0);
    *reinterpret_cast<bf16x8*>(&As[srow + 64][schunk]) =
        *reinterpret_cast<const bf16x8*>(aptr + (size_t)64 * K_ + k0);
    *reinterpret_cast<bf16x8*>(&Bs[srow][schunk]) =
        *reinterpret_cast<const bf16x8*>(bptr + k0);
    *reinterpret_cast<bf16x8*>(&Bs[srow + 64][schunk]) =
        *reinterpret_cast<const bf16x8*>(bptr + (size_t)64 * K_ + k0);
    __syncthreads();
    bf16x8 af[4], bfr[4];
#pragma unroll
    for (int m = 0; m < 4; ++m)
      af[m] = *reinterpret_cast<const bf16x8*>(&As[wm * 64 + m * 16 + l15][kslot]);
#pragma unroll
    for (int n = 0; n < 4; ++n)
      bfr[n] = *reinterpret_cast<const bf16x8*>(&Bs[wn * 64 + n * 16 + l15][kslot]);
#pragma unroll
    for (int m = 0; m < 4; ++m)
#pragma unroll
      for (int n = 0; n < 4; ++n)
        acc[m][n] = __builtin_amdgcn_mfma_f32_16x16x32_bf16(af[m], bfr[n], acc[m][n], 0, 0, 0);
    __syncthreads();
  }

  const int colbase = bn * 128 + wn * 64;
  const int rowbase = bm * 128 + wm * 64;
  if (QKV) {
    const int sec = (bn * 128) >> 10;  // 0=q 1=k 2=v (block-uniform)
#pragma unroll
    for (int n = 0; n < 4; ++n) {
      const int col = colbase + n * 16 + l15;
      const float bv = bias[col];
      const int cc = col & 1023;
      const int h = cc >> 6, d = cc & 63;
#pragma unroll
      for (int m = 0; m < 4; ++m) {
        const int row0 = rowbase + m * 16 + lg * 4;
        const int b = row0 >> 11, t0 = row0 & 2047;
        if (sec == 2) {
          bf16x4 pv;
#pragma unroll
          for (int r = 0; r < 4; ++r) pv[r] = to_bf16(acc[m][n][r] + bv);
          *reinterpret_cast<bf16x4*>(&vo[((size_t)(b * 16 + h) * 64 + d) * 2048 + t0]) = pv;
        } else if (sec == 0) {
#pragma unroll
          for (int r = 0; r < 4; ++r)
            qo[((size_t)(b * 16 + h) * 2048 + t0 + r) * 64 + d] =
                to_bf16((acc[m][n][r] + bv) * 0.125f);
        } else {
#pragma unroll
          for (int r = 0; r < 4; ++r)
            ko[((size_t)(b * 16 + h) * 2048 + t0 + r) * 64 + d] = to_bf16(acc[m][n][r] + bv);
        }
      }
    }
  } else {
#pragma unroll
    for (int n = 0; n < 4; ++n) {
      const int col = colbase + n * 16 + l15;
      const float bv = bias[col];
#pragma unroll
      for (int m = 0; m < 4; ++m) {
#pragma unroll
        for (int r = 0; r < 4; ++r) {
          const int row = rowbase + m * 16 + lg * 4 + r;
          co[(size_t)row * 1024 + col] = acc[m][n][r] + bv;
        }
      }
    }
  }
}

// ---------------- causal flash attention v2.1 ----------------
// Swapped-operand 32x32x16 MFMA; softmax fully in-register (T12 structure).
// Cross-lane exchange via __shfl_xor(.,32) — unambiguous semantics (permlane32_swap
// direction assumption was the R6 failure; re-introduce only with a green baseline).
// q,k: [B,H,T,D] bf16 (q pre-scaled by 1/8). vT: [B,H,D,T] bf16. o: [B,T,C] bf16.
__device__ __forceinline__ int pack_bf2(float lo, float hi) {
  bf16x2 t; t[0] = (bf16)lo; t[1] = (bf16)hi;
  return __builtin_bit_cast(int, t);
}

// Build PV B-fragment (16-k window starting at reg R0 of pf) from in-register P.
// Lane (l31,h) holds P[q=l31][koff=(r&3)+8*(r>>2)+4h]; B-frag needs elem j = k=8h+j.
// Per-lane pairs: a={0,1}+4h  b2={2,3}+4h  c={8,9}+4h  d2={10,11}+4h (k rel. to window).
// dword0 = h? partner_c : a      ({k0k1} / {k8k9})
// dword1 = h? partner_d : b2
// dword2 = h? c : partner_a      ({k4k5} / {k12k13})
// dword3 = h? d2 : partner_b
template <int R0>
__device__ __forceinline__ bf16x8 pack_pstep(f32x16 pf, int h) {
  int a  = pack_bf2(pf[R0 + 0], pf[R0 + 1]);
  int b2 = pack_bf2(pf[R0 + 2], pf[R0 + 3]);
  int c  = pack_bf2(pf[R0 + 4], pf[R0 + 5]);
  int d2 = pack_bf2(pf[R0 + 6], pf[R0 + 7]);
  int pa = __shfl_xor(a, 32);
  int pb = __shfl_xor(b2, 32);
  int pc = __shfl_xor(c, 32);
  int pd = __shfl_xor(d2, 32);
  int4v pi = {h ? pc : a, h ? pd : b2, h ? c : pa, h ? d2 : pb};
  return __builtin_bit_cast(bf16x8, pi);
}

__global__ __launch_bounds__(256) void attn_kernel(
    const bf16* __restrict__ q, const bf16* __restrict__ k,
    const bf16* __restrict__ vT, bf16* __restrict__ o) {
  const int bid = blockIdx.x;
  const int swz = (bid & 7) * 64 + (bid >> 3);  // XCD-contiguous: 8 heads per XCD (KV L2-resident)
  const int bh = swz >> 3;
  const int pr = swz & 7;
  const int tid = threadIdx.x;
  const int lane = tid & 63, w = tid >> 6;
  const int l31 = lane & 31, hi = lane >> 5;
  const char* qp = (const char*)(q + (size_t)bh * T_ * D_);
  const char* kp = (const char*)(k + (size_t)bh * T_ * D_);
  const char* vp = (const char*)(vT + (size_t)bh * D_ * T_);
  const int lofKQ = l31 * 128 + hi * 16;   // K/Q row stride 128B
  const int lofV  = l31 * 4096 + hi * 16;  // vT row stride 4096B
  const int bb = bh >> 4, hh = bh & 15;
  bf16* obase = o + (size_t)bb * T_ * C_ + hh * 64;

#pragma unroll
  for (int half = 0; half < 2; ++half) {
    const int qt = half ? (15 - pr) : pr;  // causal load-balance pairing
    const int qrow0 = qt * 128 + w * 32;
    const int qg = qrow0 + l31;

    bf16x8 qf[4];
#pragma unroll
    for (int s = 0; s < 4; ++s)
      qf[s] = *reinterpret_cast<const bf16x8*>(qp + (size_t)qrow0 * 128 + s * 32 + lofKQ);

    f32x16 ot0 = {}, ot1 = {};
    float mrun = -INFINITY, lrun = 0.f;

    for (int tb = 0; tb < qrow0 + 32; tb += 64) {
      // QK^T (swapped): st = S^T, lane holds 32 k-values for q = l31
      f32x16 st0 = {}, st1 = {};
#pragma unroll
      for (int s = 0; s < 4; ++s) {
        bf16x8 k0 = *reinterpret_cast<const bf16x8*>(kp + (size_t)tb * 128 + s * 32 + lofKQ);
        bf16x8 k1 = *reinterpret_cast<const bf16x8*>(kp + (size_t)(tb + 32) * 128 + s * 32 + lofKQ);
        st0 = __builtin_amdgcn_mfma_f32_32x32x16_bf16(k0, qf[s], st0, 0, 0, 0);
        st1 = __builtin_amdgcn_mfma_f32_32x32x16_bf16(k1, qf[s], st1, 0, 0, 0);
      }
      // V A-fragments: issue loads early, consumed after softmax (latency hide)
      bf16x8 va[2][4];
#pragma unroll
      for (int dt = 0; dt < 2; ++dt)
#pragma unroll
        for (int s = 0; s < 4; ++s)
          va[dt][s] = *reinterpret_cast<const bf16x8*>(
              vp + (size_t)dt * 32 * 4096 + (size_t)(tb + s * 16) * 2 + lofV);
      // causal mask (diagonal tiles only)
      if (tb + 63 > qrow0) {
#pragma unroll
        for (int r = 0; r < 16; ++r) {
          const int koff = (r & 3) + 8 * (r >> 2) + 4 * hi;
          if (tb + koff > qg) st0[r] = -1e30f;
          if (tb + 32 + koff > qg) st1[r] = -1e30f;
        }
      }
      // row max: in-register tree + partner (lane^32) combine
      float mx[16];
#pragma unroll
      for (int r = 0; r < 16; ++r) mx[r] = fmaxf(st0[r], st1[r]);
#pragma unroll
      for (int d = 8; d > 0; d >>= 1)
#pragma unroll
        for (int r = 0; r < d; ++r) mx[r] = fmaxf(mx[r], mx[r + d]);
      const float pmax = fmaxf(mx[0], __shfl_xor(mx[0], 32));
      // defer-max (T13): skip O-rescale when max growth small
      if (__any(pmax > mrun + 8.f)) {
        const float mnew = fmaxf(mrun, pmax);
        const float corr = __expf(mrun - mnew);
        lrun *= corr;
#pragma unroll
        for (int r = 0; r < 16; ++r) { ot0[r] *= corr; ot1[r] *= corr; }
        mrun = mnew;
      }
#pragma unroll
      for (int r = 0; r < 16; ++r) {
        st0[r] = __expf(st0[r] - mrun);
        st1[r] = __expf(st1[r] - mrun);
      }
      // row sum: in-register tree + partner combine
      float sm[16];
#pragma unroll
      for (int r = 0; r < 16; ++r) sm[r] = st0[r] + st1[r];
#pragma unroll
      for (int d = 8; d > 0; d >>= 1)
#pragma unroll
        for (int r = 0; r < d; ++r) sm[r] += sm[r + d];
      lrun += sm[0] + __shfl_xor(sm[0], 32);
      // P -> bf16 B-fragments (pack + lane^32 exchange, no LDS)
      bf16x8 pb[4];
      pb[0] = pack_pstep<0>(st0, hi);
      pb[1] = pack_pstep<8>(st0, hi);
      pb[2] = pack_pstep<0>(st1, hi);
      pb[3] = pack_pstep<8>(st1, hi);
      // PV: O^T[d][q] — output column = q = l31, same as softmax state
#pragma unroll
      for (int s = 0; s < 4; ++s) {
        ot0 = __builtin_amdgcn_mfma_f32_32x32x16_bf16(va[0][s], pb[s], ot0, 0, 0, 0);
        ot1 = __builtin_amdgcn_mfma_f32_32x32x16_bf16(va[1][s], pb[s], ot1, 0, 0, 0);
      }
    }

    const float inv = 1.f / lrun;
    bf16* orow = obase + (size_t)qg * C_;
#pragma unroll
    for (int dt = 0; dt < 2; ++dt) {
#pragma unroll
      for (int rg = 0; rg < 4; ++rg) {
        bf16x4 pv;
#pragma unroll
        for (int j = 0; j < 4; ++j)
          pv[j] = to_bf16(((dt ? ot1 : ot0)[rg * 4 + j]) * inv);
        *reinterpret_cast<bf16x4*>(orow + dt * 32 + rg * 8 + 4 * hi) = pv;
      }
    }
  }
}

extern "C" void kernel_launch(void* const* d_in, const int* in_sizes, int n_in,
                              void* d_out, int out_size, void* d_ws, size_t ws_size,
                              hipStream_t stream) {
  const float* x      = (const float*)d_in[0];
  const float* w_attn = (const float*)d_in[1];
  const float* b_attn = (const float*)d_in[2];
  const float* w_proj = (const float*)d_in[3];
  const float* b_proj = (const float*)d_in[4];
  float* out = (float*)d_out;

  char* ws = (char*)d_ws;
  size_t off = 0;
  bf16* xb  = (bf16*)(ws + off); off += (size_t)M_ * K_ * 2;      // 16 MiB (reused as attn_out)
  bf16* wta = (bf16*)(ws + off); off += (size_t)NQKV * K_ * 2;    // 6 MiB  [3072][1024]
  bf16* wtp = (bf16*)(ws + off); off += (size_t)C_ * K_ * 2;      // 2 MiB  [1024][1024]
  bf16* qb  = (bf16*)(ws + off); off += (size_t)M_ * C_ * 2;      // 16 MiB [B,H,T,D]
  bf16* kb  = (bf16*)(ws + off); off += (size_t)M_ * C_ * 2;      // 16 MiB [B,H,T,D]
  bf16* vtb = (bf16*)(ws + off); off += (size_t)M_ * C_ * 2;      // 16 MiB [B,H,D,T]
  bf16* attn_out = xb;  // x no longer needed once QKV GEMM is done

  cvt_x_kernel<<<(M_ * K_) / (4 * 256), 256, 0, stream>>>(x, xb);
  transpose_cvt_kernel<<<dim3(NQKV / 32, K_ / 32), dim3(32, 8), 0, stream>>>(w_attn, wta, K_, NQKV);
  transpose_cvt_kernel<<<dim3(C_ / 32, K_ / 32), dim3(32, 8), 0, stream>>>(w_proj, wtp, K_, C_);
  gemm_kernel<true><<<dim3(M_ / 128, NQKV / 128), 256, 0, stream>>>(
      xb, wta, b_attn, qb, kb, vtb, nullptr);
  attn_kernel<<<64 * 8, 256, 0, stream>>>(qb, kb, vtb, attn_out);
  gemm_kernel<false><<<dim3(M_ / 128, C_ / 128), 256, 0, stream>>>(
      attn_out, wtp, b_proj, nullptr, nullptr, nullptr, out);
}

// Round 12
// 308.010 us; speedup vs baseline: 1.6766x; 1.0512x over previous
//
#include <hip/hip_runtime.h>
#include <hip/hip_bf16.h>
#include <math.h>

typedef __bf16 bf16;
typedef __bf16 bf16x8 __attribute__((ext_vector_type(8)));
typedef __bf16 bf16x4 __attribute__((ext_vector_type(4)));
typedef __bf16 bf16x2 __attribute__((ext_vector_type(2)));
typedef float f32x4 __attribute__((ext_vector_type(4)));
typedef float f32x16 __attribute__((ext_vector_type(16)));
typedef int int4v __attribute__((ext_vector_type(4)));

static constexpr int B_ = 4, T_ = 2048, C_ = 1024, H_ = 16, D_ = 64;
static constexpr int M_ = B_ * T_;   // 8192 rows
static constexpr int NQKV = 3 * C_;  // 3072
static constexpr int K_ = C_;        // 1024 (GEMM reduction dim)

__device__ __forceinline__ bf16 to_bf16(float f) { return (bf16)f; }

// async global->LDS, 16B per lane; LDS dest = wave-uniform base + lane*16
__device__ __forceinline__ void gload_lds16(const void* g, void* l) {
  __builtin_amdgcn_global_load_lds(
      (const __attribute__((address_space(1))) void*)g,
      (__attribute__((address_space(3))) void*)l, 16, 0, 0);
}

// ---------------- fp32 -> bf16 elementwise convert (x) ----------------
__global__ void cvt_x_kernel(const float* __restrict__ in, bf16* __restrict__ out) {
  int i = (blockIdx.x * blockDim.x + threadIdx.x) * 4;
  float4 v = *reinterpret_cast<const float4*>(in + i);
  bf16x4 o;
  o[0] = to_bf16(v.x); o[1] = to_bf16(v.y); o[2] = to_bf16(v.z); o[3] = to_bf16(v.w);
  *reinterpret_cast<bf16x4*>(out + i) = o;
}

// ------------- fp32 [ROWS][COLS] -> bf16 [COLS][ROWS] transpose -------------
__global__ void transpose_cvt_kernel(const float* __restrict__ in, bf16* __restrict__ out,
                                     int ROWS, int COLS) {
  __shared__ float tile[32][33];
  int c0 = blockIdx.x * 32, r0 = blockIdx.y * 32;
  int tx = threadIdx.x, ty = threadIdx.y;  // 32 x 8
#pragma unroll
  for (int i = 0; i < 32; i += 8)
    tile[ty + i][tx] = in[(size_t)(r0 + ty + i) * COLS + c0 + tx];
  __syncthreads();
#pragma unroll
  for (int i = 0; i < 32; i += 8)
    out[(size_t)(c0 + ty + i) * ROWS + r0 + tx] = to_bf16(tile[tx][ty + i]);
}

// ---------------- bf16 MFMA GEMM v2: 128x128 tile, BK=64 ----------------
// global_load_lds w16 staging into LINEAR LDS [128][64] with XOR k-slot swizzle
// (G21: inverse-swizzled global source + swizzled ds_read; involution = XOR).
template <bool QKV>
__global__ __launch_bounds__(256) void gemm_kernel(
    const bf16* __restrict__ A, const bf16* __restrict__ Bt,
    const float* __restrict__ bias,
    bf16* __restrict__ qo, bf16* __restrict__ ko, bf16* __restrict__ vo,
    float* __restrict__ co) {
  __shared__ bf16 As[128 * 64];  // row*64 + slot*8 elems; row stride 128B
  __shared__ bf16 Bs[128 * 64];
  const int bm = blockIdx.x, bn = blockIdx.y;
  const int tid = threadIdx.x;
  const int lane = tid & 63, wave = tid >> 6;
  const int wm = wave >> 1, wn = wave & 1;  // 2x2 waves, 64x64 each
  const int l15 = lane & 15, lg = lane >> 4;
  const int l3 = lane >> 3, l7 = lane & 7;
  const int sslot = l7 ^ l3;  // source k-slot: row&7 == l3 for all staging calls

  // staging source pointers: wave stages rows [wave*32, wave*32+32), 4 calls x 8 rows
  const bf16* asrc[4];
  const bf16* bsrc[4];
#pragma unroll
  for (int j = 0; j < 4; ++j) {
    const int row = wave * 32 + j * 8 + l3;
    asrc[j] = A + (size_t)(bm * 128 + row) * K_ + sslot * 8;
    bsrc[j] = Bt + (size_t)(bn * 128 + row) * K_ + sslot * 8;
  }

  f32x4 acc[4][4] = {};

  for (int k0 = 0; k0 < K_; k0 += 64) {
#pragma unroll
    for (int j = 0; j < 4; ++j) {
      gload_lds16(asrc[j] + k0, &As[(wave * 32 + j * 8) * 64]);
      gload_lds16(bsrc[j] + k0, &Bs[(wave * 32 + j * 8) * 64]);
    }
    __syncthreads();  // drains vmcnt (global_load_lds) before reads
    bf16x8 af[4][2], bf[4][2];
#pragma unroll
    for (int m = 0; m < 4; ++m)
#pragma unroll
      for (int kk = 0; kk < 2; ++kk)
        af[m][kk] = *reinterpret_cast<const bf16x8*>(
            &As[(wm * 64 + m * 16 + l15) * 64 + (((kk * 4 + lg) ^ (l15 & 7)) * 8)]);
#pragma unroll
    for (int n = 0; n < 4; ++n)
#pragma unroll
      for (int kk = 0; kk < 2; ++kk)
        bf[n][kk] = *reinterpret_cast<const bf16x8*>(
            &Bs[(wn * 64 + n * 16 + l15) * 64 + (((kk * 4 + lg) ^ (l15 & 7)) * 8)]);
#pragma unroll
    for (int kk = 0; kk < 2; ++kk)
#pragma unroll
      for (int m = 0; m < 4; ++m)
#pragma unroll
        for (int n = 0; n < 4; ++n)
          acc[m][n] =
              __builtin_amdgcn_mfma_f32_16x16x32_bf16(af[m][kk], bf[n][kk], acc[m][n], 0, 0, 0);
    __syncthreads();  // protect LDS from next-step overwrite
  }

  const int colbase = bn * 128 + wn * 64;
  const int rowbase = bm * 128 + wm * 64;
  if (QKV) {
    const int sec = (bn * 128) >> 10;  // 0=q 1=k 2=v (block-uniform)
#pragma unroll
    for (int n = 0; n < 4; ++n) {
      const int col = colbase + n * 16 + l15;
      const float bv = bias[col];
      const int cc = col & 1023;
      const int h = cc >> 6, d = cc & 63;
#pragma unroll
      for (int m = 0; m < 4; ++m) {
        const int row0 = rowbase + m * 16 + lg * 4;
        const int b = row0 >> 11, t0 = row0 & 2047;
        if (sec == 2) {
          bf16x4 pv;
#pragma unroll
          for (int r = 0; r < 4; ++r) pv[r] = to_bf16(acc[m][n][r] + bv);
          *reinterpret_cast<bf16x4*>(&vo[((size_t)(b * 16 + h) * 64 + d) * 2048 + t0]) = pv;
        } else if (sec == 0) {
#pragma unroll
          for (int r = 0; r < 4; ++r)
            qo[((size_t)(b * 16 + h) * 2048 + t0 + r) * 64 + d] =
                to_bf16((acc[m][n][r] + bv) * 0.125f);
        } else {
#pragma unroll
          for (int r = 0; r < 4; ++r)
            ko[((size_t)(b * 16 + h) * 2048 + t0 + r) * 64 + d] = to_bf16(acc[m][n][r] + bv);
        }
      }
    }
  } else {
#pragma unroll
    for (int n = 0; n < 4; ++n) {
      const int col = colbase + n * 16 + l15;
      const float bv = bias[col];
#pragma unroll
      for (int m = 0; m < 4; ++m) {
#pragma unroll
        for (int r = 0; r < 4; ++r) {
          const int row = rowbase + m * 16 + lg * 4 + r;
          co[(size_t)row * 1024 + col] = acc[m][n][r] + bv;
        }
      }
    }
  }
}

// ---------------- causal flash attention v2.2 ----------------
// Swapped-operand 32x32x16 MFMA; softmax fully in-register; no LDS.
// Grid: 1024 blocks = 64 heads x 16 q-tiles, one 128-row tile per block
// (4 waves x 32 rows). LPT dispatch: qt descending within each XCD so long
// tiles start first; 4096 waves = 16 waves/CU (vs 8 with pairing).
__device__ __forceinline__ int pack_bf2(float lo, float hi) {
  bf16x2 t; t[0] = (bf16)lo; t[1] = (bf16)hi;
  return __builtin_bit_cast(int, t);
}

template <int R0>
__device__ __forceinline__ bf16x8 pack_pstep(f32x16 pf, int h) {
  int a  = pack_bf2(pf[R0 + 0], pf[R0 + 1]);
  int b2 = pack_bf2(pf[R0 + 2], pf[R0 + 3]);
  int c  = pack_bf2(pf[R0 + 4], pf[R0 + 5]);
  int d2 = pack_bf2(pf[R0 + 6], pf[R0 + 7]);
  int pa = __shfl_xor(a, 32);
  int pb = __shfl_xor(b2, 32);
  int pc = __shfl_xor(c, 32);
  int pd = __shfl_xor(d2, 32);
  int4v pi = {h ? pc : a, h ? pd : b2, h ? c : pa, h ? d2 : pb};
  return __builtin_bit_cast(bf16x8, pi);
}

__global__ __launch_bounds__(256) void attn_kernel(
    const bf16* __restrict__ q, const bf16* __restrict__ k,
    const bf16* __restrict__ vT, bf16* __restrict__ o) {
  const int bid = blockIdx.x;          // 0..1023
  const int xcd = bid & 7;
  const int local = bid >> 3;          // 0..127 within XCD
  const int qt = 15 - (local >> 3);    // long-first (LPT)
  const int bh = xcd * 8 + (local & 7);  // 8 heads per XCD -> KV L2-resident
  const int tid = threadIdx.x;
  const int lane = tid & 63, w = tid >> 6;
  const int l31 = lane & 31, hi = lane >> 5;
  const char* qp = (const char*)(q + (size_t)bh * T_ * D_);
  const char* kp = (const char*)(k + (size_t)bh * T_ * D_);
  const char* vp = (const char*)(vT + (size_t)bh * D_ * T_);
  const int lofKQ = l31 * 128 + hi * 16;   // K/Q row stride 128B
  const int lofV  = l31 * 4096 + hi * 16;  // vT row stride 4096B
  const int bb = bh >> 4, hh = bh & 15;
  bf16* obase = o + (size_t)bb * T_ * C_ + hh * 64;

  const int qrow0 = qt * 128 + w * 32;
  const int qg = qrow0 + l31;

  bf16x8 qf[4];
#pragma unroll
  for (int s = 0; s < 4; ++s)
    qf[s] = *reinterpret_cast<const bf16x8*>(qp + (size_t)qrow0 * 128 + s * 32 + lofKQ);

  f32x16 ot0 = {}, ot1 = {};
  float mrun = -INFINITY, lrun = 0.f;

  for (int tb = 0; tb < qrow0 + 32; tb += 64) {
    // QK^T (swapped): st = S^T, lane holds 32 k-values for q = l31
    f32x16 st0 = {}, st1 = {};
#pragma unroll
    for (int s = 0; s < 4; ++s) {
      bf16x8 k0 = *reinterpret_cast<const bf16x8*>(kp + (size_t)tb * 128 + s * 32 + lofKQ);
      bf16x8 k1 = *reinterpret_cast<const bf16x8*>(kp + (size_t)(tb + 32) * 128 + s * 32 + lofKQ);
      st0 = __builtin_amdgcn_mfma_f32_32x32x16_bf16(k0, qf[s], st0, 0, 0, 0);
      st1 = __builtin_amdgcn_mfma_f32_32x32x16_bf16(k1, qf[s], st1, 0, 0, 0);
    }
    // V A-fragments: issue loads early, consumed after softmax (latency hide)
    bf16x8 va[2][4];
#pragma unroll
    for (int dt = 0; dt < 2; ++dt)
#pragma unroll
      for (int s = 0; s < 4; ++s)
        va[dt][s] = *reinterpret_cast<const bf16x8*>(
            vp + (size_t)dt * 32 * 4096 + (size_t)(tb + s * 16) * 2 + lofV);
    // causal mask (diagonal tiles only)
    if (tb + 63 > qrow0) {
#pragma unroll
      for (int r = 0; r < 16; ++r) {
        const int koff = (r & 3) + 8 * (r >> 2) + 4 * hi;
        if (tb + koff > qg) st0[r] = -1e30f;
        if (tb + 32 + koff > qg) st1[r] = -1e30f;
      }
    }
    // row max: in-register tree + partner (lane^32) combine
    float mx[16];
#pragma unroll
    for (int r = 0; r < 16; ++r) mx[r] = fmaxf(st0[r], st1[r]);
#pragma unroll
    for (int d = 8; d > 0; d >>= 1)
#pragma unroll
      for (int r = 0; r < d; ++r) mx[r] = fmaxf(mx[r], mx[r + d]);
    const float pmax = fmaxf(mx[0], __shfl_xor(mx[0], 32));
    // defer-max (T13): skip O-rescale when max growth small
    if (__any(pmax > mrun + 8.f)) {
      const float mnew = fmaxf(mrun, pmax);
      const float corr = __expf(mrun - mnew);
      lrun *= corr;
#pragma unroll
      for (int r = 0; r < 16; ++r) { ot0[r] *= corr; ot1[r] *= corr; }
      mrun = mnew;
    }
#pragma unroll
    for (int r = 0; r < 16; ++r) {
      st0[r] = __expf(st0[r] - mrun);
      st1[r] = __expf(st1[r] - mrun);
    }
    // row sum: in-register tree + partner combine
    float sm[16];
#pragma unroll
    for (int r = 0; r < 16; ++r) sm[r] = st0[r] + st1[r];
#pragma unroll
    for (int d = 8; d > 0; d >>= 1)
#pragma unroll
      for (int r = 0; r < d; ++r) sm[r] += sm[r + d];
    lrun += sm[0] + __shfl_xor(sm[0], 32);
    // P -> bf16 B-fragments (pack + lane^32 exchange, no LDS)
    bf16x8 pb[4];
    pb[0] = pack_pstep<0>(st0, hi);
    pb[1] = pack_pstep<8>(st0, hi);
    pb[2] = pack_pstep<0>(st1, hi);
    pb[3] = pack_pstep<8>(st1, hi);
    // PV: O^T[d][q] — output column = q = l31, same as softmax state
#pragma unroll
    for (int s = 0; s < 4; ++s) {
      ot0 = __builtin_amdgcn_mfma_f32_32x32x16_bf16(va[0][s], pb[s], ot0, 0, 0, 0);
      ot1 = __builtin_amdgcn_mfma_f32_32x32x16_bf16(va[1][s], pb[s], ot1, 0, 0, 0);
    }
  }

  const float inv = 1.f / lrun;
  bf16* orow = obase + (size_t)qg * C_;
#pragma unroll
  for (int dt = 0; dt < 2; ++dt) {
#pragma unroll
    for (int rg = 0; rg < 4; ++rg) {
      bf16x4 pv;
#pragma unroll
      for (int j = 0; j < 4; ++j)
        pv[j] = to_bf16(((dt ? ot1 : ot0)[rg * 4 + j]) * inv);
      *reinterpret_cast<bf16x4*>(orow + dt * 32 + rg * 8 + 4 * hi) = pv;
    }
  }
}

extern "C" void kernel_launch(void* const* d_in, const int* in_sizes, int n_in,
                              void* d_out, int out_size, void* d_ws, size_t ws_size,
                              hipStream_t stream) {
  const float* x      = (const float*)d_in[0];
  const float* w_attn = (const float*)d_in[1];
  const float* b_attn = (const float*)d_in[2];
  const float* w_proj = (const float*)d_in[3];
  const float* b_proj = (const float*)d_in[4];
  float* out = (float*)d_out;

  char* ws = (char*)d_ws;
  size_t off = 0;
  bf16* xb  = (bf16*)(ws + off); off += (size_t)M_ * K_ * 2;      // 16 MiB (reused as attn_out)
  bf16* wta = (bf16*)(ws + off); off += (size_t)NQKV * K_ * 2;    // 6 MiB  [3072][1024]
  bf16* wtp = (bf16*)(ws + off); off += (size_t)C_ * K_ * 2;      // 2 MiB  [1024][1024]
  bf16* qb  = (bf16*)(ws + off); off += (size_t)M_ * C_ * 2;      // 16 MiB [B,H,T,D]
  bf16* kb  = (bf16*)(ws + off); off += (size_t)M_ * C_ * 2;      // 16 MiB [B,H,T,D]
  bf16* vtb = (bf16*)(ws + off); off += (size_t)M_ * C_ * 2;      // 16 MiB [B,H,D,T]
  bf16* attn_out = xb;  // x no longer needed once QKV GEMM is done

  cvt_x_kernel<<<(M_ * K_) / (4 * 256), 256, 0, stream>>>(x, xb);
  transpose_cvt_kernel<<<dim3(NQKV / 32, K_ / 32), dim3(32, 8), 0, stream>>>(w_attn, wta, K_, NQKV);
  transpose_cvt_kernel<<<dim3(C_ / 32, K_ / 32), dim3(32, 8), 0, stream>>>(w_proj, wtp, K_, C_);
  gemm_kernel<true><<<dim3(M_ / 128, NQKV / 128), 256, 0, stream>>>(
      xb, wta, b_attn, qb, kb, vtb, nullptr);
  attn_kernel<<<1024, 256, 0, stream>>>(qb, kb, vtb, attn_out);
  gemm_kernel<false><<<dim3(M_ / 128, C_ / 128), 256, 0, stream>>>(
      attn_out, wtp, b_proj, nullptr, nullptr, nullptr, out);
}